// Round 1
// baseline (315.552 us; speedup 1.0000x reference)
//
#include <hip/hip_runtime.h>

#define NN 256
#define CC 16
#define NC (NN*CC)      // 4096 floats per (i,j) row
#define OC (18*CC)      // 288 output channels

// ---------------- K0: neighbor lists (ballot compaction) ----------------
__global__ void k_build_nbr(const float* __restrict__ A, short* __restrict__ nbr,
                            int* __restrict__ deg) {
    int a = blockIdx.x;
    int t = threadIdx.x;            // 0..255
    int lane = t & 63, wave = t >> 6;
    bool pred = A[a*NN + t] != 0.0f;
    unsigned long long m = __ballot(pred);
    __shared__ int wcnt[4];
    if (lane == 0) wcnt[wave] = __popcll(m);
    __syncthreads();
    int off = 0;
    for (int w = 0; w < wave; ++w) off += wcnt[w];
    if (pred) {
        int pos = off + __popcll(m & ((1ull << lane) - 1ull));
        nbr[a*NN + pos] = (short)t;
    }
    if (t == 0) deg[a] = wcnt[0] + wcnt[1] + wcnt[2] + wcnt[3];
}

// ---------------- K1: c3[a,b,c]=sum_{j in N(a)} T[a,j,b,c]
//                      c5[a,b,c]=sum_{i in N(a)} T[i,a,b,c]
// block per (a, half-row); contiguous streaming, register accumulators.
__global__ __launch_bounds__(512) void k_c3c5(const float* __restrict__ T,
                                              const short* __restrict__ nbr,
                                              const int* __restrict__ deg,
                                              float* __restrict__ out) {
    int a = blockIdx.x >> 1;
    int h = blockIdx.x & 1;
    int t = threadIdx.x;            // 0..511
    int idx = h*512 + t;            // float4 index within the 1024-float4 row
    int d = deg[a];
    const short* nb = nbr + a*NN;
    float4 acc3 = make_float4(0.f,0.f,0.f,0.f);
    float4 acc5 = make_float4(0.f,0.f,0.f,0.f);
    for (int e = 0; e < d; ++e) {
        int j = nb[e];
        float4 v = ((const float4*)(T + (size_t)(a*NN + j)*NC))[idx];
        float4 w = ((const float4*)(T + (size_t)(j*NN + a)*NC))[idx];
        acc3.x += v.x; acc3.y += v.y; acc3.z += v.z; acc3.w += v.w;
        acc5.x += w.x; acc5.y += w.y; acc5.z += w.z; acc5.w += w.w;
    }
    int b  = idx >> 2;
    int c0 = (idx & 3) << 2;
    size_t o = (size_t)(a*NN + b)*OC;
    *(float4*)(out + o + 2*CC + c0) = acc3;   // c3 -> channel block 2
    *(float4*)(out + o + 4*CC + c0) = acc5;   // c5 -> channel block 4
}

// ---------------- K2: c1[a,b,c]=sum_{k in N(a)} T[a,b,k,c]
//                      c2[a,b,c]=sum_{k in N(a)} T[b,a,k,c]
__global__ __launch_bounds__(512) void k_c1c2(const float* __restrict__ T,
                                              const short* __restrict__ nbr,
                                              const int* __restrict__ deg,
                                              float* __restrict__ out) {
    int a = blockIdx.x & 255;
    int q = blockIdx.x >> 8;        // b-quarter 0..3
    int t = threadIdx.x;
    int c = t & 15, g = t >> 4;     // 32 groups of 16 lanes
    int d = deg[a];
    const short* nb = nbr + a*NN;
    for (int b = q*64 + g; b < q*64 + 64; b += 32) {
        const float* r1 = T + (size_t)(a*NN + b)*NC + c;
        const float* r2 = T + (size_t)(b*NN + a)*NC + c;
        float s1 = 0.f, s2 = 0.f;
        for (int e = 0; e < d; ++e) {
            int k = nb[e]*CC;
            s1 += r1[k];
            s2 += r2[k];
        }
        size_t o = (size_t)(a*NN + b)*OC;
        out[o + 0*CC + c] = s1;
        out[o + 1*CC + c] = s2;
    }
}

// ---------------- K3: c4[a,b,c]=sum_{j in N(a)} T[b,j,a,c]
//                      c6[a,b,c]=sum_{i in N(a)} T[i,b,a,c]
__global__ __launch_bounds__(512) void k_c4c6(const float* __restrict__ T,
                                              const short* __restrict__ nbr,
                                              const int* __restrict__ deg,
                                              float* __restrict__ out) {
    int b = blockIdx.x & 255;
    int q = blockIdx.x >> 8;        // a-quarter 0..3
    int t = threadIdx.x;
    int c = t & 15, g = t >> 4;
    for (int a = q*64 + g; a < q*64 + 64; a += 32) {
        int d = deg[a];
        const short* nb = nbr + a*NN;
        float s4 = 0.f, s6 = 0.f;
        for (int e = 0; e < d; ++e) {
            int m = nb[e];
            s4 += T[(size_t)(b*NN + m)*NC + a*CC + c];   // T[b, j=m, a, c]
            s6 += T[(size_t)(m*NN + b)*NC + a*CC + c];   // T[i=m, b, a, c]
        }
        size_t o = (size_t)(a*NN + b)*OC;
        out[o + 3*CC + c] = s4;   // c4 -> channel block 3
        out[o + 5*CC + c] = s6;   // c6 -> channel block 5
    }
}

// ---------------- K4: six diagonal extractions (channels 6..11) ----------------
__global__ void k_diag(const float* __restrict__ T, float* __restrict__ out) {
    int a = blockIdx.x;
    int t = threadIdx.x;            // 256
    int c = t & 15, g = t >> 4;     // 16 groups
    for (int b = g; b < NN; b += 16) {
        size_t o = (size_t)(a*NN + b)*OC;
        out[o + 6*CC  + c] = T[(size_t)(a*NN + a)*NC + b*CC + c]; // c7  = T[a,a,b,c]
        out[o + 7*CC  + c] = T[(size_t)(b*NN + b)*NC + a*CC + c]; // c8  = T[b,b,a,c]
        out[o + 8*CC  + c] = T[(size_t)(a*NN + b)*NC + a*CC + c]; // c9  = T[a,b,a,c]
        out[o + 9*CC  + c] = T[(size_t)(b*NN + a)*NC + b*CC + c]; // c10 = T[b,a,b,c]
        out[o + 10*CC + c] = T[(size_t)(a*NN + b)*NC + b*CC + c]; // c11 = T[a,b,b,c]
        out[o + 11*CC + c] = T[(size_t)(b*NN + a)*NC + a*CC + c]; // c12 = T[b,a,a,c]
    }
}

// ---------------- K5a: v1,v2,v3 from materialized c1,c2,c6 ----------------
// v1[a,c]=sum_{b in N(a)} c1[a,b,c]; v2 from c2; v3 from c6.
__global__ void k_vsum(const float* __restrict__ out_ro,
                       const short* __restrict__ nbr, const int* __restrict__ deg,
                       float* __restrict__ vbuf) {
    int a = blockIdx.x;
    int t = threadIdx.x;            // 256
    int c = t & 15, p = t >> 4;     // 16 partial groups
    int d = deg[a];
    const short* nb = nbr + a*NN;
    float s1 = 0.f, s2 = 0.f, s3 = 0.f;
    for (int e = p; e < d; e += 16) {
        int b = nb[e];
        size_t o = (size_t)(a*NN + b)*OC;
        s1 += out_ro[o + 0*CC + c];
        s2 += out_ro[o + 1*CC + c];
        s3 += out_ro[o + 5*CC + c];
    }
    __shared__ float red[3][16][16];   // [v][p][c]
    red[0][p][c] = s1; red[1][p][c] = s2; red[2][p][c] = s3;
    __syncthreads();
    if (t < 48) {
        int v = t >> 4, cc = t & 15;
        float s = 0.f;
        for (int pp = 0; pp < 16; ++pp) s += red[v][pp][cc];
        vbuf[(v*NN + a)*CC + cc] = s;
    }
}

// ---------------- K5b: broadcast v's into channels 12..17 ----------------
__global__ void k_broadcast(const float* __restrict__ vbuf, float* __restrict__ out) {
    int a = blockIdx.x;
    int t = threadIdx.x;            // 256
    int c = t & 15, g = t >> 4;
    float v1a = vbuf[(0*NN + a)*CC + c];
    float v2a = vbuf[(1*NN + a)*CC + c];
    float v3a = vbuf[(2*NN + a)*CC + c];
    for (int b = g; b < NN; b += 16) {
        float v1b = vbuf[(0*NN + b)*CC + c];
        float v2b = vbuf[(1*NN + b)*CC + c];
        float v3b = vbuf[(2*NN + b)*CC + c];
        size_t o = (size_t)(a*NN + b)*OC;
        out[o + 12*CC + c] = v1a;   // c13 = v1[a]
        out[o + 13*CC + c] = v1b;   // c14 = v1[b]
        out[o + 14*CC + c] = v2a;   // c15 = v2[a]
        out[o + 15*CC + c] = v2b;   // c16 = v2[b]
        out[o + 16*CC + c] = v3a;   // c17 = v3[a]
        out[o + 17*CC + c] = v3b;   // c18 = v3[b]
    }
}

extern "C" void kernel_launch(void* const* d_in, const int* in_sizes, int n_in,
                              void* d_out, int out_size, void* d_ws, size_t ws_size,
                              hipStream_t stream) {
    const float* T = (const float*)d_in[0];   // activations (256,256,256,16) f32
    const float* A = (const float*)d_in[1];   // adjacency (256,256) f32, {0,1}, symmetric
    float* out = (float*)d_out;

    // workspace layout: nbr (short[256][256]) | deg (int[256]) | vbuf (float[3][256][16])
    short* nbr  = (short*)d_ws;
    int*   deg  = (int*)((char*)d_ws + NN*NN*sizeof(short));
    float* vbuf = (float*)((char*)d_ws + NN*NN*sizeof(short) + NN*sizeof(int));

    hipLaunchKernelGGL(k_build_nbr, dim3(NN),   dim3(NN),  0, stream, A, nbr, deg);
    hipLaunchKernelGGL(k_c3c5,      dim3(NN*2), dim3(512), 0, stream, T, nbr, deg, out);
    hipLaunchKernelGGL(k_c1c2,      dim3(NN*4), dim3(512), 0, stream, T, nbr, deg, out);
    hipLaunchKernelGGL(k_c4c6,      dim3(NN*4), dim3(512), 0, stream, T, nbr, deg, out);
    hipLaunchKernelGGL(k_diag,      dim3(NN),   dim3(256), 0, stream, T, out);
    hipLaunchKernelGGL(k_vsum,      dim3(NN),   dim3(256), 0, stream, out, nbr, deg, vbuf);
    hipLaunchKernelGGL(k_broadcast, dim3(NN),   dim3(256), 0, stream, vbuf, out);
}

// Round 2
// 233.838 us; speedup vs baseline: 1.3494x; 1.3494x over previous
//
#include <hip/hip_runtime.h>

#define NN 256
#define CC 16
#define NC (NN*CC)      // 4096 floats per (i,j) row
#define OC (18*CC)      // 288 output channels (72 float4)

__device__ __forceinline__ void add4(float4& a, const float4 b) {
    a.x += b.x; a.y += b.y; a.z += b.z; a.w += b.w;
}
__device__ __forceinline__ void mad4(float4& a, const float4 b, float m) {
    a.x += b.x*m; a.y += b.y*m; a.z += b.z*m; a.w += b.w*m;
}

// ---------------- K0: neighbor lists (ballot compaction) ----------------
__global__ void k_build_nbr(const float* __restrict__ A, short* __restrict__ nbr,
                            int* __restrict__ deg) {
    int a = blockIdx.x;
    int t = threadIdx.x;            // 0..255
    int lane = t & 63, wave = t >> 6;
    bool pred = A[a*NN + t] != 0.0f;
    unsigned long long m = __ballot(pred);
    __shared__ int wcnt[4];
    if (lane == 0) wcnt[wave] = __popcll(m);
    __syncthreads();
    int off = 0;
    for (int w = 0; w < wave; ++w) off += wcnt[w];
    if (pred) {
        int pos = off + __popcll(m & ((1ull << lane) - 1ull));
        nbr[a*NN + pos] = (short)t;
    }
    if (t == 0) deg[a] = wcnt[0] + wcnt[1] + wcnt[2] + wcnt[3];
}

// ---------------- K1: fused c1..c12 + v-partials ----------------
// block = (a, quarter q of b); thread: v = t&3 (float4 slot), bl = t>>2, b = q*64+bl.
// All loads are float4 (64B per 4 lanes, coalesced). Writes cover out[.., 0:192)
// contiguously. v1/v2/v3 partial sums over b in this quarter go to vpart.
__global__ __launch_bounds__(256) void k_fused(const float4* __restrict__ T4,
                                               const float* __restrict__ A,
                                               const short* __restrict__ nbr,
                                               const int* __restrict__ deg,
                                               float4* __restrict__ out4,
                                               float* __restrict__ vpart) {
    int a = blockIdx.x >> 2;
    int q = blockIdx.x & 3;
    int t = threadIdx.x;
    int v = t & 3, bl = t >> 2;
    int b = q*64 + bl;
    int d = deg[a];

    __shared__ short nbs[NN];
    __shared__ float red[3][64][16];
    for (int e = t; e < d; e += 256) nbs[e] = nbr[a*NN + e];
    __syncthreads();

    // float4-unit row bases (1024 float4 per (i,j) row)
    const int rowAB = (a*NN + b) << 10;
    const int rowBA = (b*NN + a) << 10;
    const int slabA = a << 18;          // (a*NN)<<10
    const int slabB = b << 18;
    const int offB  = (b << 2) + v;     // chunk offset b*4+v inside a row
    const int offA  = (a << 2) + v;

    float4 z = make_float4(0.f,0.f,0.f,0.f);
    float4 acc1=z, acc2=z, acc3=z, acc4=z, acc5=z, acc6=z;
    #pragma unroll 2
    for (int e = 0; e < d; ++e) {
        int k = nbs[e];
        float4 x1 = T4[rowAB + (k<<2) + v];          // T[a,b,k,:]
        float4 x2 = T4[rowBA + (k<<2) + v];          // T[b,a,k,:]
        float4 x3 = T4[slabA + (k<<10) + offB];      // T[a,k,b,:]
        float4 x4 = T4[slabB + (k<<10) + offA];      // T[b,k,a,:]
        float4 x5 = T4[(k<<18) + (a<<10) + offB];    // T[k,a,b,:]
        float4 x6 = T4[(k<<18) + (b<<10) + offA];    // T[k,b,a,:]
        add4(acc1,x1); add4(acc2,x2); add4(acc3,x3);
        add4(acc4,x4); add4(acc5,x5); add4(acc6,x6);
    }

    // diagonals
    float4 d7  = T4[slabA + (a<<10) + offB];   // T[a,a,b,:]
    float4 d8  = T4[slabB + (b<<10) + offA];   // T[b,b,a,:]
    float4 d9  = T4[rowAB + offA];             // T[a,b,a,:]
    float4 d10 = T4[rowBA + offB];             // T[b,a,b,:]
    float4 d11 = T4[rowAB + offB];             // T[a,b,b,:]
    float4 d12 = T4[rowBA + offA];             // T[b,a,a,:]

    // write channels 0..11 : contiguous [0,192) bytes of the output row
    const int ob = (a*NN + b)*72;
    out4[ob + 0*4 + v] = acc1;
    out4[ob + 1*4 + v] = acc2;
    out4[ob + 2*4 + v] = acc3;
    out4[ob + 3*4 + v] = acc4;
    out4[ob + 4*4 + v] = acc5;
    out4[ob + 5*4 + v] = acc6;
    out4[ob + 6*4 + v] = d7;
    out4[ob + 7*4 + v] = d8;
    out4[ob + 8*4 + v] = d9;
    out4[ob + 9*4 + v] = d10;
    out4[ob +10*4 + v] = d11;
    out4[ob +11*4 + v] = d12;

    // v-partials: v1[a]=sum_{b in N(a)} c1[a,b]; v2 from c2; v3 from c6
    float m = (A[a*NN + b] != 0.0f) ? 1.0f : 0.0f;
    float4 m1=z, m2=z, m3=z;
    mad4(m1, acc1, m); mad4(m2, acc2, m); mad4(m3, acc6, m);
    red[0][bl][v*4+0]=m1.x; red[0][bl][v*4+1]=m1.y; red[0][bl][v*4+2]=m1.z; red[0][bl][v*4+3]=m1.w;
    red[1][bl][v*4+0]=m2.x; red[1][bl][v*4+1]=m2.y; red[1][bl][v*4+2]=m2.z; red[1][bl][v*4+3]=m2.w;
    red[2][bl][v*4+0]=m3.x; red[2][bl][v*4+1]=m3.y; red[2][bl][v*4+2]=m3.z; red[2][bl][v*4+3]=m3.w;
    __syncthreads();
    if (t < 48) {
        int vi = t >> 4, cc = t & 15;
        float s = 0.f;
        for (int i = 0; i < 64; ++i) s += red[vi][i][cc];
        vpart[((a*4 + q)*3 + vi)*CC + cc] = s;
    }
}

// ---------------- K2: sum quarter partials -> vbuf ----------------
__global__ void k_vred(const float* __restrict__ vpart, float* __restrict__ vbuf) {
    int idx = blockIdx.x*256 + threadIdx.x;   // 0..12287
    int vi = idx >> 12, rem = idx & 4095;
    int a = rem >> 4, cc = rem & 15;
    float s = 0.f;
    for (int q = 0; q < 4; ++q) s += vpart[((a*4 + q)*3 + vi)*CC + cc];
    vbuf[(vi*NN + a)*CC + cc] = s;
}

// ---------------- K3: broadcast v's into channels 12..17 ----------------
__global__ __launch_bounds__(256) void k_broadcast(const float4* __restrict__ vb4,
                                                   float4* __restrict__ out4) {
    int a = blockIdx.x;
    int t = threadIdx.x;
    int v = t & 3, bl = t >> 2;
    float4 v1a = vb4[(0*NN + a)*4 + v];
    float4 v2a = vb4[(1*NN + a)*4 + v];
    float4 v3a = vb4[(2*NN + a)*4 + v];
    for (int b = bl; b < NN; b += 64) {
        float4 v1b = vb4[(0*NN + b)*4 + v];
        float4 v2b = vb4[(1*NN + b)*4 + v];
        float4 v3b = vb4[(2*NN + b)*4 + v];
        int ob = (a*NN + b)*72;
        out4[ob + 48 + v] = v1a;   // c13
        out4[ob + 52 + v] = v1b;   // c14
        out4[ob + 56 + v] = v2a;   // c15
        out4[ob + 60 + v] = v2b;   // c16
        out4[ob + 64 + v] = v3a;   // c17
        out4[ob + 68 + v] = v3b;   // c18
    }
}

extern "C" void kernel_launch(void* const* d_in, const int* in_sizes, int n_in,
                              void* d_out, int out_size, void* d_ws, size_t ws_size,
                              hipStream_t stream) {
    const float* T = (const float*)d_in[0];   // (256,256,256,16) f32
    const float* A = (const float*)d_in[1];   // (256,256) f32 {0,1} symmetric
    float* out = (float*)d_out;

    // ws layout: nbr short[256*256] | deg int[256] | vpart f32[256*4*3*16] | vbuf f32[3*256*16]
    char* w = (char*)d_ws;
    short* nbr  = (short*)w;                          w += NN*NN*sizeof(short);
    int*   deg  = (int*)w;                            w += NN*sizeof(int);
    float* vpart= (float*)w;                          w += NN*4*3*CC*sizeof(float);
    float* vbuf = (float*)w;

    hipLaunchKernelGGL(k_build_nbr, dim3(NN),   dim3(NN),  0, stream, A, nbr, deg);
    hipLaunchKernelGGL(k_fused,     dim3(NN*4), dim3(256), 0, stream,
                       (const float4*)T, A, nbr, deg, (float4*)out, vpart);
    hipLaunchKernelGGL(k_vred,      dim3(48),   dim3(256), 0, stream, vpart, vbuf);
    hipLaunchKernelGGL(k_broadcast, dim3(NN),   dim3(256), 0, stream,
                       (const float4*)vbuf, (float4*)out);
}